// Round 2
// baseline (3235.634 us; speedup 1.0000x reference)
//
#include <hip/hip_runtime.h>
#include <hip/hip_bf16.h>

#define F_IN   128
#define F_HID  16
#define F_OUT  2

// ---------------- kernel 1: degree count (int atomics) ----------------
__global__ void k_count(const int* __restrict__ dst, unsigned* __restrict__ cnt, int E) {
    int t = blockIdx.x * blockDim.x + threadIdx.x;
    if (t < E) atomicAdd(&cnt[dst[t]], 1u);
}

// ---------------- kernel 2: dinv = rsqrt(deg+1) ----------------
__global__ void k_dinv(const unsigned* __restrict__ cnt, float* __restrict__ dinv, int n) {
    int i = blockIdx.x * blockDim.x + threadIdx.x;
    if (i < n) dinv[i] = rsqrtf((float)cnt[i] + 1.0f);
}

// ---------------- kernel 3: h1 = x @ W1 (no bias) ----------------
__global__ __launch_bounds__(256) void k_gemm1(const float* __restrict__ x,
                                               const float* __restrict__ W1,
                                               float* __restrict__ h1, int n) {
    __shared__ float Ws[F_IN * F_HID];  // 8 KB
    for (int i = threadIdx.x; i < F_IN * F_HID; i += 256) Ws[i] = W1[i];
    __syncthreads();
    int node = blockIdx.x * 256 + threadIdx.x;
    if (node >= n) return;
    float acc[F_HID];
#pragma unroll
    for (int c = 0; c < F_HID; c++) acc[c] = 0.f;
    const float4* row = (const float4*)(x + (size_t)node * F_IN);
    for (int kk = 0; kk < F_IN / 4; kk++) {
        float4 p = row[kk];
        const float* w0 = &Ws[(kk * 4 + 0) * F_HID];
        const float* w1 = &Ws[(kk * 4 + 1) * F_HID];
        const float* w2 = &Ws[(kk * 4 + 2) * F_HID];
        const float* w3 = &Ws[(kk * 4 + 3) * F_HID];
#pragma unroll
        for (int c = 0; c < F_HID; c++)
            acc[c] += p.x * w0[c] + p.y * w1[c] + p.z * w2[c] + p.w * w3[c];
    }
    float4* out = (float4*)(h1 + (size_t)node * F_HID);
#pragma unroll
    for (int q = 0; q < 4; q++)
        out[q] = make_float4(acc[q * 4 + 0], acc[q * 4 + 1], acc[q * 4 + 2], acc[q * 4 + 3]);
}

// ---------------- kernel 4: scatter layer 1 (4 threads / edge) ----------------
__global__ void k_scatter1(const int* __restrict__ src, const int* __restrict__ dst,
                           const float* __restrict__ dinv, const float* __restrict__ h1,
                           float* __restrict__ agg1, int E) {
    int t = blockIdx.x * blockDim.x + threadIdx.x;
    if (t >= E * 4) return;
    int e = t >> 2, c4 = (t & 3) << 2;
    int s = src[e], d = dst[e];
    float w = dinv[s] * dinv[d];
    float4 hv = *(const float4*)(h1 + (size_t)s * F_HID + c4);
    float* a = agg1 + (size_t)d * F_HID + c4;
    unsafeAtomicAdd(a + 0, hv.x * w);
    unsafeAtomicAdd(a + 1, hv.y * w);
    unsafeAtomicAdd(a + 2, hv.z * w);
    unsafeAtomicAdd(a + 3, hv.w * w);
}

// ---------------- kernel 5: combine1 + ReLU + GEMM2 ----------------
__global__ __launch_bounds__(256) void k_combine1(const float* __restrict__ agg1,
                                                  const float* __restrict__ h1,
                                                  const float* __restrict__ dinv,
                                                  const float* __restrict__ b1,
                                                  const float* __restrict__ W2,
                                                  float* __restrict__ h2, int n) {
    __shared__ float b1s[F_HID], W2s[F_HID * F_OUT];
    if (threadIdx.x < F_HID) b1s[threadIdx.x] = b1[threadIdx.x];
    if (threadIdx.x < F_HID * F_OUT) W2s[threadIdx.x] = W2[threadIdx.x];
    __syncthreads();
    int i = blockIdx.x * 256 + threadIdx.x;
    if (i >= n) return;
    float di = dinv[i], dd = di * di;
    const float4* av = (const float4*)(agg1 + (size_t)i * F_HID);
    const float4* hv = (const float4*)(h1 + (size_t)i * F_HID);
    float s0 = 0.f, s1 = 0.f;
#pragma unroll
    for (int q = 0; q < 4; q++) {
        float4 a = av[q], h = hv[q];
        float o0 = fmaxf(0.f, a.x + h.x * dd + b1s[q * 4 + 0]);
        float o1 = fmaxf(0.f, a.y + h.y * dd + b1s[q * 4 + 1]);
        float o2 = fmaxf(0.f, a.z + h.z * dd + b1s[q * 4 + 2]);
        float o3 = fmaxf(0.f, a.w + h.w * dd + b1s[q * 4 + 3]);
        s0 += o0 * W2s[(q * 4 + 0) * 2] + o1 * W2s[(q * 4 + 1) * 2] +
              o2 * W2s[(q * 4 + 2) * 2] + o3 * W2s[(q * 4 + 3) * 2];
        s1 += o0 * W2s[(q * 4 + 0) * 2 + 1] + o1 * W2s[(q * 4 + 1) * 2 + 1] +
              o2 * W2s[(q * 4 + 2) * 2 + 1] + o3 * W2s[(q * 4 + 3) * 2 + 1];
    }
    *(float2*)(h2 + (size_t)i * 2) = make_float2(s0, s1);
}

// ---------------- kernel 6: scatter layer 2 (1 thread / edge) ----------------
__global__ void k_scatter2(const int* __restrict__ src, const int* __restrict__ dst,
                           const float* __restrict__ dinv, const float* __restrict__ h2,
                           float* __restrict__ agg2, int E) {
    int e = blockIdx.x * blockDim.x + threadIdx.x;
    if (e >= E) return;
    int s = src[e], d = dst[e];
    float w = dinv[s] * dinv[d];
    float2 hv = *(const float2*)(h2 + (size_t)s * 2);
    unsafeAtomicAdd(agg2 + (size_t)d * 2 + 0, hv.x * w);
    unsafeAtomicAdd(agg2 + (size_t)d * 2 + 1, hv.y * w);
}

// ---------------- kernel 7: combine2 + log_softmax ----------------
__global__ void k_final(const float* __restrict__ agg2, const float* __restrict__ h2,
                        const float* __restrict__ dinv, const float* __restrict__ b2,
                        float2* __restrict__ out, int n) {
    int i = blockIdx.x * blockDim.x + threadIdx.x;
    if (i >= n) return;
    float di = dinv[i], dd = di * di;
    float2 a = *(const float2*)(agg2 + (size_t)i * 2);
    float2 h = *(const float2*)(h2 + (size_t)i * 2);
    float v0 = a.x + h.x * dd + b2[0];
    float v1 = a.y + h.y * dd + b2[1];
    float m = fmaxf(v0, v1);
    float lse = m + log1pf(expf(fminf(v0, v1) - m));
    out[i] = make_float2(v0 - lse, v1 - lse);
}

extern "C" void kernel_launch(void* const* d_in, const int* in_sizes, int n_in,
                              void* d_out, int out_size, void* d_ws, size_t ws_size,
                              hipStream_t stream) {
    const float* x  = (const float*)d_in[0];
    const int*   ei = (const int*)d_in[1];
    const float* W1 = (const float*)d_in[2];
    const float* b1 = (const float*)d_in[3];
    const float* W2 = (const float*)d_in[4];
    const float* b2 = (const float*)d_in[5];

    int n = in_sizes[0] / F_IN;   // 500000
    int E = in_sizes[1] / 2;      // 8000000
    const int* src = ei;
    const int* dst = ei + E;

    char* ws = (char*)d_ws;
    size_t nb = (size_t)n;
    float*    dinv = (float*)ws;                          // 4n
    unsigned* cnt  = (unsigned*)(ws + 4 * nb);            // 4n
    float*    h1   = (float*)(ws + 8 * nb);               // 64n
    float*    agg1 = (float*)(ws + 72 * nb);              // 64n
    float*    h2   = (float*)(ws + 136 * nb);             // 8n
    float*    agg2 = (float*)(ws + 144 * nb);             // 8n
    // total 152n = 76 MB

    hipMemsetAsync(cnt, 0, 4 * nb, stream);
    hipMemsetAsync(agg1, 0, 64 * nb, stream);
    hipMemsetAsync(agg2, 0, 8 * nb, stream);

    int bE  = (E + 255) / 256;
    int bE4 = (E * 4 + 255) / 256;
    int bN  = (n + 255) / 256;

    k_count<<<bE, 256, 0, stream>>>(dst, cnt, E);
    k_dinv<<<bN, 256, 0, stream>>>(cnt, dinv, n);
    k_gemm1<<<bN, 256, 0, stream>>>(x, W1, h1, n);
    k_scatter1<<<bE4, 256, 0, stream>>>(src, dst, dinv, h1, agg1, E);
    k_combine1<<<bN, 256, 0, stream>>>(agg1, h1, dinv, b1, W2, h2, n);
    k_scatter2<<<bE, 256, 0, stream>>>(src, dst, dinv, h2, agg2, E);
    k_final<<<bN, 256, 0, stream>>>(agg2, h2, dinv, b2, (float2*)d_out, n);
}

// Round 3
// 1628.014 us; speedup vs baseline: 1.9875x; 1.9875x over previous
//
#include <hip/hip_runtime.h>

#define F_IN   128
#define F_HID  16

// ---------------- degree count (int atomics) ----------------
__global__ void k_count(const int* __restrict__ dst, unsigned* __restrict__ cnt, int E) {
    int t = blockIdx.x * blockDim.x + threadIdx.x;
    if (t < E) atomicAdd(&cnt[dst[t]], 1u);
}

// ---------------- dinv = rsqrt(deg+1) ----------------
__global__ void k_dinv(const unsigned* __restrict__ cnt, float* __restrict__ dinv, int n) {
    int i = blockIdx.x * blockDim.x + threadIdx.x;
    if (i < n) dinv[i] = rsqrtf((float)cnt[i] + 1.0f);
}

// ---------------- exclusive scan, 3 kernels (1024 elems/block) ----------------
__global__ __launch_bounds__(1024) void k_scan1(const unsigned* __restrict__ cnt,
                                                unsigned* __restrict__ row_ptr,
                                                unsigned* __restrict__ bsum, int n) {
    __shared__ unsigned s[1024];
    int g = blockIdx.x * 1024 + threadIdx.x;
    unsigned v = (g < n) ? cnt[g] : 0u;
    s[threadIdx.x] = v;
    __syncthreads();
    for (int off = 1; off < 1024; off <<= 1) {
        unsigned t = (threadIdx.x >= off) ? s[threadIdx.x - off] : 0u;
        __syncthreads();
        s[threadIdx.x] += t;
        __syncthreads();
    }
    if (g < n) row_ptr[g] = s[threadIdx.x] - v;            // exclusive within block
    if (threadIdx.x == 1023) bsum[blockIdx.x] = s[1023];   // block total
}

__global__ __launch_bounds__(1024) void k_scan2(unsigned* __restrict__ bsum, int nb) {
    __shared__ unsigned s[1024];
    unsigned v = (threadIdx.x < nb) ? bsum[threadIdx.x] : 0u;
    s[threadIdx.x] = v;
    __syncthreads();
    for (int off = 1; off < 1024; off <<= 1) {
        unsigned t = (threadIdx.x >= off) ? s[threadIdx.x - off] : 0u;
        __syncthreads();
        s[threadIdx.x] += t;
        __syncthreads();
    }
    if (threadIdx.x < nb) bsum[threadIdx.x] = s[threadIdx.x] - v;  // exclusive
}

__global__ __launch_bounds__(1024) void k_scan3(unsigned* __restrict__ row_ptr,
                                                const unsigned* __restrict__ bsum,
                                                int n, int E) {
    int g = blockIdx.x * 1024 + threadIdx.x;
    if (g < n) row_ptr[g] += bsum[blockIdx.x];
    if (g == 0) row_ptr[n] = (unsigned)E;
}

// ---------------- CSR placement (int atomics only) ----------------
__global__ void k_place(const int* __restrict__ src, const int* __restrict__ dst,
                        const unsigned* __restrict__ row_ptr, unsigned* __restrict__ fill,
                        int* __restrict__ adj, int E) {
    int e = blockIdx.x * blockDim.x + threadIdx.x;
    if (e >= E) return;
    int d = dst[e];
    unsigned pos = row_ptr[d] + atomicAdd(&fill[d], 1u);
    adj[pos] = src[e];
}

// ---------------- h1 = x @ W1 ----------------
__global__ __launch_bounds__(256) void k_gemm1(const float* __restrict__ x,
                                               const float* __restrict__ W1,
                                               float* __restrict__ h1, int n) {
    __shared__ float Ws[F_IN * F_HID];  // 8 KB
    for (int i = threadIdx.x; i < F_IN * F_HID; i += 256) Ws[i] = W1[i];
    __syncthreads();
    int node = blockIdx.x * 256 + threadIdx.x;
    if (node >= n) return;
    float acc[F_HID];
#pragma unroll
    for (int c = 0; c < F_HID; c++) acc[c] = 0.f;
    const float4* row = (const float4*)(x + (size_t)node * F_IN);
    for (int kk = 0; kk < F_IN / 4; kk++) {
        float4 p = row[kk];
        const float* w0 = &Ws[(kk * 4 + 0) * F_HID];
        const float* w1 = &Ws[(kk * 4 + 1) * F_HID];
        const float* w2 = &Ws[(kk * 4 + 2) * F_HID];
        const float* w3 = &Ws[(kk * 4 + 3) * F_HID];
#pragma unroll
        for (int c = 0; c < F_HID; c++)
            acc[c] += p.x * w0[c] + p.y * w1[c] + p.z * w2[c] + p.w * w3[c];
    }
    float4* out = (float4*)(h1 + (size_t)node * F_HID);
#pragma unroll
    for (int q = 0; q < 4; q++)
        out[q] = make_float4(acc[q * 4 + 0], acc[q * 4 + 1], acc[q * 4 + 2], acc[q * 4 + 3]);
}

// ---- layer-1 aggregate + self-loop + bias + ReLU + GEMM2 -> h2 ----
// 16 lanes per node; lane j owns feature j. Per edge, the 16 lanes read one
// contiguous 64B segment of h1 (coalesced); dinv[d] factored out of the sum.
__global__ __launch_bounds__(256) void k_agg1(const int* __restrict__ adj,
                                              const unsigned* __restrict__ row_ptr,
                                              const float* __restrict__ dinv,
                                              const float* __restrict__ h1,
                                              const float* __restrict__ b1,
                                              const float* __restrict__ W2,
                                              float2* __restrict__ h2, int n) {
    int lane = threadIdx.x & 15;
    int i = (blockIdx.x * 256 + threadIdx.x) >> 4;
    if (i >= n) return;
    unsigned e0 = row_ptr[i], e1 = row_ptr[i + 1];
    float acc = 0.f;
    for (unsigned e = e0; e < e1; e++) {
        int s = adj[e];
        acc += dinv[s] * h1[(size_t)s * F_HID + lane];
    }
    float di = dinv[i];
    acc = acc * di + h1[(size_t)i * F_HID + lane] * (di * di) + b1[lane];
    float v = fmaxf(acc, 0.f);
    float c0 = v * W2[lane * 2 + 0];
    float c1 = v * W2[lane * 2 + 1];
#pragma unroll
    for (int off = 1; off < 16; off <<= 1) {
        c0 += __shfl_xor(c0, off, 64);
        c1 += __shfl_xor(c1, off, 64);
    }
    if (lane == 0) h2[i] = make_float2(c0, c1);
}

// ---- layer-2 aggregate + self-loop + bias + log_softmax -> out ----
// 16 lanes per node split the edge list (coalesced adj reads), reduce via shuffles.
__global__ __launch_bounds__(256) void k_agg2(const int* __restrict__ adj,
                                              const unsigned* __restrict__ row_ptr,
                                              const float* __restrict__ dinv,
                                              const float2* __restrict__ h2,
                                              const float* __restrict__ b2,
                                              float2* __restrict__ out, int n) {
    int lane = threadIdx.x & 15;
    int i = (blockIdx.x * 256 + threadIdx.x) >> 4;
    if (i >= n) return;
    unsigned e0 = row_ptr[i], e1 = row_ptr[i + 1];
    float a0 = 0.f, a1 = 0.f;
    for (unsigned e = e0 + lane; e < e1; e += 16) {
        int s = adj[e];
        float w = dinv[s];
        float2 hv = h2[s];
        a0 += w * hv.x;
        a1 += w * hv.y;
    }
#pragma unroll
    for (int off = 1; off < 16; off <<= 1) {
        a0 += __shfl_xor(a0, off, 64);
        a1 += __shfl_xor(a1, off, 64);
    }
    if (lane == 0) {
        float di = dinv[i];
        float2 hs = h2[i];
        float v0 = a0 * di + hs.x * (di * di) + b2[0];
        float v1 = a1 * di + hs.y * (di * di) + b2[1];
        float m = fmaxf(v0, v1);
        float lse = m + log1pf(expf(fminf(v0, v1) - m));
        out[i] = make_float2(v0 - lse, v1 - lse);
    }
}

extern "C" void kernel_launch(void* const* d_in, const int* in_sizes, int n_in,
                              void* d_out, int out_size, void* d_ws, size_t ws_size,
                              hipStream_t stream) {
    const float* x  = (const float*)d_in[0];
    const int*   ei = (const int*)d_in[1];
    const float* W1 = (const float*)d_in[2];
    const float* b1 = (const float*)d_in[3];
    const float* W2 = (const float*)d_in[4];
    const float* b2 = (const float*)d_in[5];

    int n = in_sizes[0] / F_IN;   // 500000
    int E = in_sizes[1] / 2;      // 8000000
    const int* src = ei;
    const int* dst = ei + E;

    // workspace layout (bytes), n=500000 -> 4n = 2,000,000 (16-aligned)
    char* ws = (char*)d_ws;
    size_t nb = (size_t)n;
    float*    dinv    = (float*)ws;                         // 4n
    unsigned* cnt     = (unsigned*)(ws + 4 * nb);           // 4n (reused as fill)
    unsigned* row_ptr = (unsigned*)(ws + 8 * nb);           // 4n + 64
    unsigned* bsum    = (unsigned*)(ws + 12 * nb + 64);     // 4096
    float*    h1      = (float*)(ws + 12 * nb + 4160);      // 64n
    float2*   h2      = (float2*)(ws + 76 * nb + 4160);     // 8n
    int*      adj     = (int*)(ws + 84 * nb + 4160);        // 4E
    // total = 88n + 4E + 4160 ~= 76.0 MB

    int bE = (E + 255) / 256;
    int bN = (n + 255) / 256;
    int SB = (n + 1023) / 1024;          // scan blocks (489)
    int bG = (n * 16 + 255) / 256;       // agg blocks (16 lanes/node)

    hipMemsetAsync(cnt, 0, 4 * nb, stream);
    k_count<<<bE, 256, 0, stream>>>(dst, cnt, E);
    k_dinv <<<bN, 256, 0, stream>>>(cnt, dinv, n);
    k_scan1<<<SB, 1024, 0, stream>>>(cnt, row_ptr, bsum, n);
    k_scan2<<<1, 1024, 0, stream>>>(bsum, SB);
    k_scan3<<<SB, 1024, 0, stream>>>(row_ptr, bsum, n, E);
    hipMemsetAsync(cnt, 0, 4 * nb, stream);   // reuse cnt as fill
    k_place<<<bE, 256, 0, stream>>>(src, dst, row_ptr, cnt, adj, E);
    k_gemm1<<<bN, 256, 0, stream>>>(x, W1, h1, n);
    k_agg1 <<<bG, 256, 0, stream>>>(adj, row_ptr, dinv, h1, b1, W2, h2, n);
    k_agg2 <<<bG, 256, 0, stream>>>(adj, row_ptr, dinv, h2, b2, (float2*)d_out, n);
}

// Round 4
// 1105.561 us; speedup vs baseline: 2.9267x; 1.4726x over previous
//
#include <hip/hip_runtime.h>

#define F_IN   128
#define F_HID  16
#define NPB    2048          // nodes per bucket
#define NPB_SH 11
#define SRC_BITS 19
#define SRC_MASK 0x7FFFFu

// ---------------- bucket histogram (dst >> 11) ----------------
__global__ __launch_bounds__(256) void k_hist1(const int* __restrict__ dst,
                                               unsigned* __restrict__ bcnt, int E) {
    __shared__ unsigned h[256];
    h[threadIdx.x] = 0;
    __syncthreads();
    for (int i = blockIdx.x * 256 + threadIdx.x; i < E; i += gridDim.x * 256)
        atomicAdd(&h[((unsigned)dst[i]) >> NPB_SH], 1u);
    __syncthreads();
    if (h[threadIdx.x]) atomicAdd(&bcnt[threadIdx.x], h[threadIdx.x]);
}

// ---------------- scan 256 bucket counts ----------------
__global__ __launch_bounds__(256) void k_scanb(const unsigned* __restrict__ bcnt,
                                               unsigned* __restrict__ bbase,
                                               unsigned* __restrict__ bfill,
                                               unsigned* __restrict__ row_ptr,
                                               int n, int E) {
    __shared__ unsigned s[256];
    unsigned v = bcnt[threadIdx.x];
    s[threadIdx.x] = v;
    __syncthreads();
    for (int off = 1; off < 256; off <<= 1) {
        unsigned t = (threadIdx.x >= (unsigned)off) ? s[threadIdx.x - off] : 0u;
        __syncthreads();
        s[threadIdx.x] += t;
        __syncthreads();
    }
    unsigned incl = s[threadIdx.x];
    bbase[threadIdx.x + 1] = incl;
    bfill[threadIdx.x] = incl - v;    // exclusive
    if (threadIdx.x == 0) { bbase[0] = 0; row_ptr[n] = (unsigned)E; }
}

// ---------------- bin edges into buckets (packed (ldst<<19)|src) ----------------
__global__ __launch_bounds__(1024) void k_bin(const int* __restrict__ src,
                                              const int* __restrict__ dst,
                                              unsigned* __restrict__ bfill,
                                              unsigned* __restrict__ binned, int E) {
    __shared__ unsigned hist[256], fill2[256], runbase[256];
    if (threadIdx.x < 256) { hist[threadIdx.x] = 0; fill2[threadIdx.x] = 0; }
    __syncthreads();
    unsigned val[8]; unsigned bkt[8]; bool ok[8];
    int base = blockIdx.x * 8192;
#pragma unroll
    for (int k = 0; k < 8; k++) {
        int e = base + k * 1024 + threadIdx.x;
        ok[k] = e < E;
        if (ok[k]) {
            unsigned d = (unsigned)dst[e];
            unsigned s = (unsigned)src[e];
            bkt[k] = d >> NPB_SH;
            val[k] = ((d & (NPB - 1)) << SRC_BITS) | s;
            atomicAdd(&hist[bkt[k]], 1u);
        }
    }
    __syncthreads();
    if (threadIdx.x < 256 && hist[threadIdx.x])
        runbase[threadIdx.x] = atomicAdd(&bfill[threadIdx.x], hist[threadIdx.x]);
    __syncthreads();
#pragma unroll
    for (int k = 0; k < 8; k++) {
        if (ok[k]) {
            unsigned pos = runbase[bkt[k]] + atomicAdd(&fill2[bkt[k]], 1u);
            binned[pos] = val[k];
        }
    }
}

// ---- per-bucket: node histogram -> row_ptr, dinv, place adj (LDS atomics only) ----
__global__ __launch_bounds__(1024) void k_bucket(const unsigned* __restrict__ binned,
                                                 const unsigned* __restrict__ bbase,
                                                 int* __restrict__ adj,
                                                 unsigned* __restrict__ row_ptr,
                                                 float* __restrict__ dinv,
                                                 int n) {
    __shared__ unsigned cnt[NPB];
    __shared__ unsigned base[NPB];
    __shared__ unsigned pairs[1024];
    int b = blockIdx.x;
    unsigned estart = bbase[b], eend = bbase[b + 1];
    unsigned ecount = eend - estart;
    int nb_base = b * NPB;
    cnt[threadIdx.x] = 0; cnt[threadIdx.x + 1024] = 0;
    __syncthreads();
    for (unsigned i = threadIdx.x; i < ecount; i += 1024)
        atomicAdd(&cnt[binned[estart + i] >> SRC_BITS], 1u);
    __syncthreads();
    // scan 2048 counters: pair-sum + Hillis-Steele over 1024
    unsigned c0 = cnt[2 * threadIdx.x], c1 = cnt[2 * threadIdx.x + 1];
    pairs[threadIdx.x] = c0 + c1;
    __syncthreads();
    for (int off = 1; off < 1024; off <<= 1) {
        unsigned t = (threadIdx.x >= (unsigned)off) ? pairs[threadIdx.x - off] : 0u;
        __syncthreads();
        pairs[threadIdx.x] += t;
        __syncthreads();
    }
    unsigned ip = pairs[threadIdx.x];
    unsigned e0 = ip - c0 - c1;         // exclusive offset of node 2t
    unsigned e1 = ip - c1;              // exclusive offset of node 2t+1
    base[2 * threadIdx.x] = e0;
    base[2 * threadIdx.x + 1] = e1;
    int g0 = nb_base + 2 * threadIdx.x, g1 = g0 + 1;
    if (g0 < n) { row_ptr[g0] = estart + e0; dinv[g0] = rsqrtf((float)c0 + 1.0f); }
    if (g1 < n) { row_ptr[g1] = estart + e1; dinv[g1] = rsqrtf((float)c1 + 1.0f); }
    __syncthreads();
    cnt[threadIdx.x] = 0; cnt[threadIdx.x + 1024] = 0;   // reuse as fill
    __syncthreads();
    for (unsigned i = threadIdx.x; i < ecount; i += 1024) {
        unsigned v = binned[estart + i];
        unsigned ldst = v >> SRC_BITS;
        unsigned pos = base[ldst] + atomicAdd(&cnt[ldst], 1u);
        adj[estart + pos] = (int)(v & SRC_MASK);
    }
}

// ---------------- h1 = x @ W1 ----------------
__global__ __launch_bounds__(256) void k_gemm1(const float* __restrict__ x,
                                               const float* __restrict__ W1,
                                               float* __restrict__ h1, int n) {
    __shared__ float Ws[F_IN * F_HID];  // 8 KB
    for (int i = threadIdx.x; i < F_IN * F_HID; i += 256) Ws[i] = W1[i];
    __syncthreads();
    int node = blockIdx.x * 256 + threadIdx.x;
    if (node >= n) return;
    float acc[F_HID];
#pragma unroll
    for (int c = 0; c < F_HID; c++) acc[c] = 0.f;
    const float4* row = (const float4*)(x + (size_t)node * F_IN);
    for (int kk = 0; kk < F_IN / 4; kk++) {
        float4 p = row[kk];
        const float* w0 = &Ws[(kk * 4 + 0) * F_HID];
        const float* w1 = &Ws[(kk * 4 + 1) * F_HID];
        const float* w2 = &Ws[(kk * 4 + 2) * F_HID];
        const float* w3 = &Ws[(kk * 4 + 3) * F_HID];
#pragma unroll
        for (int c = 0; c < F_HID; c++)
            acc[c] += p.x * w0[c] + p.y * w1[c] + p.z * w2[c] + p.w * w3[c];
    }
    float4* out = (float4*)(h1 + (size_t)node * F_HID);
#pragma unroll
    for (int q = 0; q < 4; q++)
        out[q] = make_float4(acc[q * 4 + 0], acc[q * 4 + 1], acc[q * 4 + 2], acc[q * 4 + 3]);
}

// ---- layer-1 aggregate + self-loop + bias + ReLU + GEMM2 -> h2 ----
__global__ __launch_bounds__(256) void k_agg1(const int* __restrict__ adj,
                                              const unsigned* __restrict__ row_ptr,
                                              const float* __restrict__ dinv,
                                              const float* __restrict__ h1,
                                              const float* __restrict__ b1,
                                              const float* __restrict__ W2,
                                              float2* __restrict__ h2, int n) {
    int lane = threadIdx.x & 15;
    int i = (blockIdx.x * 256 + threadIdx.x) >> 4;
    if (i >= n) return;
    unsigned e0 = row_ptr[i], e1 = row_ptr[i + 1];
    float acc = 0.f;
    for (unsigned e = e0; e < e1; e++) {
        int s = adj[e];
        acc += dinv[s] * h1[(size_t)s * F_HID + lane];
    }
    float di = dinv[i];
    acc = acc * di + h1[(size_t)i * F_HID + lane] * (di * di) + b1[lane];
    float v = fmaxf(acc, 0.f);
    float c0 = v * W2[lane * 2 + 0];
    float c1 = v * W2[lane * 2 + 1];
#pragma unroll
    for (int off = 1; off < 16; off <<= 1) {
        c0 += __shfl_xor(c0, off, 64);
        c1 += __shfl_xor(c1, off, 64);
    }
    if (lane == 0) h2[i] = make_float2(c0, c1);
}

// ---- layer-2 aggregate + self-loop + bias + log_softmax -> out ----
__global__ __launch_bounds__(256) void k_agg2(const int* __restrict__ adj,
                                              const unsigned* __restrict__ row_ptr,
                                              const float* __restrict__ dinv,
                                              const float2* __restrict__ h2,
                                              const float* __restrict__ b2,
                                              float2* __restrict__ out, int n) {
    int lane = threadIdx.x & 15;
    int i = (blockIdx.x * 256 + threadIdx.x) >> 4;
    if (i >= n) return;
    unsigned e0 = row_ptr[i], e1 = row_ptr[i + 1];
    float a0 = 0.f, a1 = 0.f;
    for (unsigned e = e0 + lane; e < e1; e += 16) {
        int s = adj[e];
        float w = dinv[s];
        float2 hv = h2[s];
        a0 += w * hv.x;
        a1 += w * hv.y;
    }
#pragma unroll
    for (int off = 1; off < 16; off <<= 1) {
        a0 += __shfl_xor(a0, off, 64);
        a1 += __shfl_xor(a1, off, 64);
    }
    if (lane == 0) {
        float di = dinv[i];
        float2 hs = h2[i];
        float v0 = a0 * di + hs.x * (di * di) + b2[0];
        float v1 = a1 * di + hs.y * (di * di) + b2[1];
        float m = fmaxf(v0, v1);
        float lse = m + log1pf(expf(fminf(v0, v1) - m));
        out[i] = make_float2(v0 - lse, v1 - lse);
    }
}

extern "C" void kernel_launch(void* const* d_in, const int* in_sizes, int n_in,
                              void* d_out, int out_size, void* d_ws, size_t ws_size,
                              hipStream_t stream) {
    const float* x  = (const float*)d_in[0];
    const int*   ei = (const int*)d_in[1];
    const float* W1 = (const float*)d_in[2];
    const float* b1 = (const float*)d_in[3];
    const float* W2 = (const float*)d_in[4];
    const float* b2 = (const float*)d_in[5];

    int n = in_sizes[0] / F_IN;   // 500000
    int E = in_sizes[1] / 2;      // 8000000
    const int* src = ei;
    const int* dst = ei + E;
    int B = (n + NPB - 1) / NPB;  // 245 buckets

    // workspace layout (all 64B-aligned); binned overlays h1 (binned dead before gemm1)
    char* ws = (char*)d_ws;
    size_t off = 0;
    auto alloc = [&](size_t bytes) { char* p = ws + off; off = (off + bytes + 63) & ~size_t(63); return p; };
    float*    dinv    = (float*)alloc(4 * (size_t)n);
    unsigned* row_ptr = (unsigned*)alloc(4 * ((size_t)n + 1));
    unsigned* bcnt    = (unsigned*)alloc(1024);
    unsigned* bbase   = (unsigned*)alloc(1028);
    unsigned* bfill   = (unsigned*)alloc(1024);
    char*     regionA = alloc(32000000);          // binned (4E) then h1 (64n)
    unsigned* binned  = (unsigned*)regionA;
    float*    h1      = (float*)regionA;
    int*      adj     = (int*)alloc(4 * (size_t)E);
    float2*   h2      = (float2*)alloc(8 * (size_t)n);

    int bN = (n + 255) / 256;
    int bBIN = (E + 8191) / 8192;
    int bG = (n * 16 + 255) / 256;

    hipMemsetAsync(bcnt, 0, 1024, stream);
    k_hist1 <<<1024, 256, 0, stream>>>(dst, bcnt, E);
    k_scanb <<<1, 256, 0, stream>>>(bcnt, bbase, bfill, row_ptr, n, E);
    k_bin   <<<bBIN, 1024, 0, stream>>>(src, dst, bfill, binned, E);
    k_bucket<<<B, 1024, 0, stream>>>(binned, bbase, adj, row_ptr, dinv, n);
    k_gemm1 <<<bN, 256, 0, stream>>>(x, W1, h1, n);
    k_agg1  <<<bG, 256, 0, stream>>>(adj, row_ptr, dinv, h1, b1, W2, h2, n);
    k_agg2  <<<bG, 256, 0, stream>>>(adj, row_ptr, dinv, h2, b2, (float2*)d_out, n);
}